// Round 1
// baseline (223.210 us; speedup 1.0000x reference)
//
#include <hip/hip_runtime.h>
#include <hip/hip_bf16.h>

#define N_NODES 50000
#define C 128
#define NPAD 50176            // 3136 row-tiles of 16; 392 blocks * 8 tiles
#define NTILES (NPAD / 16)
#define GEMM_BLOCKS (NTILES / 8)  // 392
#define XPREP_BLOCKS 3125         // 800000 / 256
#define WPREP_BLOCKS 256
#define CAP 48                    // padded CSR slots per node; P(deg>48)~1e-11 at lambda=12
#define EPT 4                     // edges per thread in buildfill (atomic MLP)

typedef short bf16x8 __attribute__((ext_vector_type(8)));
typedef float f32x4 __attribute__((ext_vector_type(4)));

__device__ __forceinline__ unsigned short f2bf(float f) {
    unsigned int u = __float_as_uint(f);
    unsigned int r = u + 0x7fffu + ((u >> 16) & 1u);
    return (unsigned short)(r >> 16);
}

__device__ __forceinline__ float bf2f(unsigned short b) {
    return __uint_as_float(((unsigned int)b) << 16);
}

__device__ __forceinline__ void acc8(float* a, uint4 u) {
    const unsigned int uu[4] = {u.x, u.y, u.z, u.w};
#pragma unroll
    for (int i = 0; i < 4; ++i) {
        a[2 * i] += bf2f((unsigned short)uu[i]);
        a[2 * i + 1] += bf2f((unsigned short)(uu[i] >> 16));
    }
}

// ---- fused: padded-CSR fill + x->bf16 cast + weight cast (block-range split)
//      edge section: EPT=4 edges/thread, phase-split loads->atomics->stores for MLP
__global__ __launch_bounds__(256) void buildfill_kernel(
    const int* __restrict__ src, const int* __restrict__ dst, int E, int edgeBlocks,
    int* __restrict__ cursor, int* __restrict__ csr,
    const float* __restrict__ x, unsigned short* __restrict__ Xb,
    const float* __restrict__ Wl1, const float* __restrict__ Wr1,
    const float* __restrict__ Wl2, const float* __restrict__ Wr2,
    unsigned short* __restrict__ Wc1, unsigned short* __restrict__ Wc2) {
    int b = blockIdx.x;
    if (b < edgeBlocks) {
        int e0 = b * (256 * EPT) + threadIdx.x;
        int dd[EPT], ss[EPT], slot[EPT];
        bool val[EPT];
#pragma unroll
        for (int k = 0; k < EPT; ++k) {
            int e = e0 + k * 256;
            val[k] = e < E;
            if (val[k]) {
                dd[k] = dst[e];
                ss[k] = src[e];
                val[k] = ((unsigned)dd[k] < (unsigned)N_NODES) &&
                         ((unsigned)ss[k] < (unsigned)N_NODES);
            }
        }
#pragma unroll
        for (int k = 0; k < EPT; ++k)
            if (val[k]) slot[k] = atomicAdd(cursor + dd[k], 1);
#pragma unroll
        for (int k = 0; k < EPT; ++k)
            if (val[k] && slot[k] < CAP) csr[dd[k] * CAP + slot[k]] = ss[k];
    } else if (b < edgeBlocks + XPREP_BLOCKS) {
        int t = (b - edgeBlocks) * 256 + threadIdx.x;
        if (t >= N_NODES * C / 8) return;
        const float4 a = *(const float4*)(x + (size_t)t * 8);
        const float4 c = *(const float4*)(x + (size_t)t * 8 + 4);
        unsigned short o[8] = {f2bf(a.x), f2bf(a.y), f2bf(a.z), f2bf(a.w),
                               f2bf(c.x), f2bf(c.y), f2bf(c.z), f2bf(c.w)};
        *(uint4*)(Xb + (size_t)t * 8) = *(const uint4*)o;
    } else {
        int idx = (b - edgeBlocks - XPREP_BLOCKS) * 256 + threadIdx.x;  // 65536
        int layer = idx >> 15;
        int r = idx & 32767;
        int j = r >> 8, k = r & 255;
        const float* Wl = layer ? Wl2 : Wl1;
        const float* Wr = layer ? Wr2 : Wr1;
        unsigned short* Wc = layer ? Wc2 : Wc1;
        float f = (k < 128) ? Wl[j * 128 + k] : Wr[j * 128 + (k - 128)];
        Wc[r] = f2bf(f);
    }
}

// ---- gather mean from bf16 features: one wave per node, padded CSR
//      4 rows per dwordx4 instruction: lane group g=lane>>4 owns row j+g,
//      lanes c=lane&15 cover cols c*8..c*8+7 (16B each); cross-group
//      reduction via shfl_xor(16/32) at the end.
__global__ __launch_bounds__(256) void gather_kernel(
    const unsigned short* __restrict__ feat,  // [*, 128] bf16
    const int* __restrict__ cursor, const int* __restrict__ csr,
    unsigned short* __restrict__ Fm) {
    int w = (blockIdx.x * 256 + threadIdx.x) >> 6;   // node id (one wave each)
    int lane = threadIdx.x & 63;
    if (w >= N_NODES) return;
    const int deg = min(cursor[w], CAP);
    const int g = lane >> 4;          // row group 0..3
    const int c = lane & 15;          // column block
    float a[8];
#pragma unroll
    for (int i = 0; i < 8; ++i) a[i] = 0.f;
    int myidx = (lane < deg) ? csr[w * CAP + lane] : 0;
    const unsigned short* fp = feat + c * 8;
    int j = 0;
    for (; j + 8 <= deg; j += 8) {
        int s0 = __shfl(myidx, j + g);
        int s1 = __shfl(myidx, j + 4 + g);
        const uint4 u0 = *(const uint4*)(fp + (size_t)s0 * C);
        const uint4 u1 = *(const uint4*)(fp + (size_t)s1 * C);
        acc8(a, u0);
        acc8(a, u1);
    }
    if (j + 4 <= deg) {
        int s0 = __shfl(myidx, j + g);
        const uint4 u0 = *(const uint4*)(fp + (size_t)s0 * C);
        acc8(a, u0);
        j += 4;
    }
    int rem = deg - j;   // 0..3
    if (rem) {
        int s0 = __shfl(myidx, j + ((g < rem) ? g : 0));
        if (g < rem) {
            const uint4 u0 = *(const uint4*)(fp + (size_t)s0 * C);
            acc8(a, u0);
        }
    }
    // sum the 4 row-groups
#pragma unroll
    for (int i = 0; i < 8; ++i) {
        a[i] += __shfl_xor(a[i], 16);
        a[i] += __shfl_xor(a[i], 32);
    }
    const float inv = 1.0f / fmaxf((float)deg, 1.0f);
    if (g == 0) {
        unsigned int o[4];
#pragma unroll
        for (int i = 0; i < 4; ++i)
            o[i] = (unsigned)f2bf(a[2 * i] * inv) |
                   ((unsigned)f2bf(a[2 * i + 1] * inv) << 16);
        *(uint4*)(Fm + (size_t)w * C + c * 8) = *(const uint4*)o;
    }
}

// ---- GEMM: out[n][j] = sum_k A[n][k]*Wc[j][k] + bias[j]
// A = [Fm | Self] (two [*,128] bf16 matrices), M = NPAD, N = 128, K = 256
__global__ __launch_bounds__(256) void sage_gemm(
    const unsigned short* __restrict__ Fm,    // [NPAD,128] bf16 (mean)
    const unsigned short* __restrict__ Self,  // [NPAD,128] bf16 (self feats)
    const unsigned short* __restrict__ Wc,    // [128,256] bf16
    const float* __restrict__ bias,           // [128]
    void* __restrict__ outv, int relu, int obf16) {
    __shared__ unsigned short wl[128 * 264];  // pitch 264 shorts (bank shift 4)
    for (int cidx = threadIdx.x; cidx < 4096; cidx += 256) {
        int row = cidx >> 5, chunk = cidx & 31;
        const uint4 v = *(const uint4*)(Wc + row * 256 + chunk * 8);
        *(uint4*)(&wl[row * 264 + chunk * 8]) = v;
    }
    __syncthreads();

    const int wave = threadIdx.x >> 6;
    const int lane = threadIdx.x & 63;
    const int m = lane & 15;
    const int q = lane >> 4;
    const int tile0 = blockIdx.x * 8 + wave * 2;

    const size_t rowoff = (size_t)(tile0 * 16 + m) * C + q * 8;
    const unsigned short* am = Fm + rowoff;
    const unsigned short* as = Self + rowoff;

    f32x4 acc[2][8];
#pragma unroll
    for (int t = 0; t < 2; ++t)
#pragma unroll
        for (int j = 0; j < 8; ++j) acc[t][j] = (f32x4){0.f, 0.f, 0.f, 0.f};

#pragma unroll
    for (int kt = 0; kt < 8; ++kt) {
        const unsigned short* A = (kt < 4) ? am : as;
        const int ko = (kt & 3) * 32;
        bf16x8 af0 = *(const bf16x8*)(A + ko);
        bf16x8 af1 = *(const bf16x8*)(A + 16 * C + ko);
#pragma unroll
        for (int jt = 0; jt < 8; ++jt) {
            bf16x8 bfrag = *(const bf16x8*)(&wl[(jt * 16 + m) * 264 + kt * 32 + q * 8]);
            acc[0][jt] = __builtin_amdgcn_mfma_f32_16x16x32_bf16(af0, bfrag, acc[0][jt], 0, 0, 0);
            acc[1][jt] = __builtin_amdgcn_mfma_f32_16x16x32_bf16(af1, bfrag, acc[1][jt], 0, 0, 0);
        }
    }

#pragma unroll
    for (int t = 0; t < 2; ++t) {
        int rbase = (tile0 + t) * 16 + q * 4;
#pragma unroll
        for (int r = 0; r < 4; ++r) {
            int row = rbase + r;
            if (row < N_NODES) {
#pragma unroll
                for (int jt = 0; jt < 8; ++jt) {
                    int col = jt * 16 + m;
                    float v = acc[t][jt][r] + bias[col];
                    if (relu) v = fmaxf(v, 0.0f);
                    if (obf16)
                        ((unsigned short*)outv)[(size_t)row * C + col] = f2bf(v);
                    else
                        ((float*)outv)[(size_t)row * C + col] = v;
                }
            }
        }
    }
}

extern "C" void kernel_launch(void* const* d_in, const int* in_sizes, int n_in,
                              void* d_out, int out_size, void* d_ws, size_t ws_size,
                              hipStream_t stream) {
    const float* x = (const float*)d_in[0];
    const int* edge = (const int*)d_in[1];   // int64 in reference -> int32 in harness
    const float* Wl1 = (const float*)d_in[2];
    const float* bl1 = (const float*)d_in[3];
    const float* Wr1 = (const float*)d_in[4];
    const float* Wl2 = (const float*)d_in[5];
    const float* bl2 = (const float*)d_in[6];
    const float* Wr2 = (const float*)d_in[7];
    float* out = (float*)d_out;

    const int E = in_sizes[1] / 2;
    const int* src = edge;
    const int* dst = edge + E;

    // workspace layout
    char* ws = (char*)d_ws;
    size_t off = 0;
    int* cursor = (int*)(ws + off);           off += (size_t)N_NODES * 4;           // 200 KB
    off = (off + 511) & ~511ull;
    int* csr = (int*)(ws + off);              off += (size_t)N_NODES * CAP * 4;     // 9.6 MB
    off = (off + 511) & ~511ull;
    unsigned short* Xb = (unsigned short*)(ws + off); off += (size_t)NPAD * C * 2;  // 12.8 MB
    unsigned short* Fm = (unsigned short*)(ws + off); off += (size_t)NPAD * C * 2;  // 12.8 MB
    unsigned short* h  = (unsigned short*)(ws + off); off += (size_t)NPAD * C * 2;  // 12.8 MB
    unsigned short* Wc1 = (unsigned short*)(ws + off); off += 128 * 256 * 2;
    unsigned short* Wc2 = (unsigned short*)(ws + off); off += 128 * 256 * 2;
    (void)ws_size;

    const int edgeBlocks = (E + 256 * EPT - 1) / (256 * EPT);   // 586
    const int gatherBlocks = (NPAD * 64) / 256;                 // one wave per node

    // padded-CSR build + feature/weight conversion (2 dispatches)
    hipMemsetAsync(cursor, 0, (size_t)N_NODES * 4, stream);
    buildfill_kernel<<<edgeBlocks + XPREP_BLOCKS + WPREP_BLOCKS, 256, 0, stream>>>(
        src, dst, E, edgeBlocks, cursor, csr, x, Xb, Wl1, Wr1, Wl2, Wr2, Wc1, Wc2);

    // layer 1
    gather_kernel<<<gatherBlocks, 256, 0, stream>>>(Xb, cursor, csr, Fm);
    sage_gemm<<<GEMM_BLOCKS, 256, 0, stream>>>(Fm, Xb, Wc1, bl1, h, 1, 1);

    // layer 2
    gather_kernel<<<gatherBlocks, 256, 0, stream>>>(h, cursor, csr, Fm);
    sage_gemm<<<GEMM_BLOCKS, 256, 0, stream>>>(Fm, h, Wc2, bl2, out, 0, 0);
}

// Round 2
// 208.676 us; speedup vs baseline: 1.0696x; 1.0696x over previous
//
#include <hip/hip_runtime.h>
#include <hip/hip_bf16.h>

#define N_NODES 50000
#define C 128
#define NPAD 50176            // 3136 row-tiles of 16; 392 blocks * 8 tiles
#define NTILES (NPAD / 16)
#define GEMM_BLOCKS (NTILES / 8)  // 392
#define XPREP_BLOCKS 3125         // 800000 / 256
#define WPREP_BLOCKS 256
#define CAP 48                    // padded CSR slots per node; P(deg>48)~1e-11 at lambda=12
#define CSTRIDE 32                // cursor padded to one 128B line per node (atomic line contention)

typedef short bf16x8 __attribute__((ext_vector_type(8)));
typedef float f32x4 __attribute__((ext_vector_type(4)));

__device__ __forceinline__ unsigned short f2bf(float f) {
    unsigned int u = __float_as_uint(f);
    unsigned int r = u + 0x7fffu + ((u >> 16) & 1u);
    return (unsigned short)(r >> 16);
}

__device__ __forceinline__ float bf2f(unsigned short b) {
    return __uint_as_float(((unsigned int)b) << 16);
}

__device__ __forceinline__ void acc8(float* a, uint4 u) {
    const unsigned int uu[4] = {u.x, u.y, u.z, u.w};
#pragma unroll
    for (int i = 0; i < 4; ++i) {
        a[2 * i] += bf2f((unsigned short)uu[i]);
        a[2 * i + 1] += bf2f((unsigned short)(uu[i] >> 16));
    }
}

// ---- fused: padded-CSR fill + x->bf16 cast + weight cast (block-range split)
//      edge section: EPT=1 (max TLP; EPT=4 measured regression 47->54us)
__global__ __launch_bounds__(256) void buildfill_kernel(
    const int* __restrict__ src, const int* __restrict__ dst, int E, int edgeBlocks,
    int* __restrict__ cursor, int* __restrict__ csr,
    const float* __restrict__ x, unsigned short* __restrict__ Xb,
    const float* __restrict__ Wl1, const float* __restrict__ Wr1,
    const float* __restrict__ Wl2, const float* __restrict__ Wr2,
    unsigned short* __restrict__ Wc1, unsigned short* __restrict__ Wc2) {
    int b = blockIdx.x;
    if (b < edgeBlocks) {
        int e = b * 256 + threadIdx.x;
        if (e < E) {
            int d = dst[e];
            int s = src[e];
            if ((unsigned)d < (unsigned)N_NODES && (unsigned)s < (unsigned)N_NODES) {
                int slot = atomicAdd(cursor + d * CSTRIDE, 1);
                if (slot < CAP) csr[d * CAP + slot] = s;
            }
        }
    } else if (b < edgeBlocks + XPREP_BLOCKS) {
        int t = (b - edgeBlocks) * 256 + threadIdx.x;
        if (t >= N_NODES * C / 8) return;
        const float4 a = *(const float4*)(x + (size_t)t * 8);
        const float4 c = *(const float4*)(x + (size_t)t * 8 + 4);
        unsigned short o[8] = {f2bf(a.x), f2bf(a.y), f2bf(a.z), f2bf(a.w),
                               f2bf(c.x), f2bf(c.y), f2bf(c.z), f2bf(c.w)};
        *(uint4*)(Xb + (size_t)t * 8) = *(const uint4*)o;
    } else {
        int idx = (b - edgeBlocks - XPREP_BLOCKS) * 256 + threadIdx.x;  // 65536
        int layer = idx >> 15;
        int r = idx & 32767;
        int j = r >> 8, k = r & 255;
        const float* Wl = layer ? Wl2 : Wl1;
        const float* Wr = layer ? Wr2 : Wr1;
        unsigned short* Wc = layer ? Wc2 : Wc1;
        float f = (k < 128) ? Wl[j * 128 + k] : Wr[j * 128 + (k - 128)];
        Wc[r] = f2bf(f);
    }
}

// ---- gather mean from bf16 features: one wave per node, padded CSR
//      cursor + csr loads issued concurrently (csr contents independent of deg;
//      lanes >= deg never selected by shfl). Up to 6 independent 4-row dwordx4
//      batches issued back-to-back under wave-uniform branches before any wait.
//      Rare overflow (deg > 24, P~8e-4 at lambda=12) takes a uniform loop.
__global__ __launch_bounds__(256) void gather_kernel(
    const unsigned short* __restrict__ feat,  // [*, 128] bf16
    const int* __restrict__ cursor, const int* __restrict__ csr,
    unsigned short* __restrict__ Fm) {
    int w = (blockIdx.x * 256 + threadIdx.x) >> 6;   // node id (one wave each)
    int lane = threadIdx.x & 63;
    if (w >= N_NODES) return;
    const int g = lane >> 4;          // row group 0..3
    const int c = lane & 15;          // column block
    // issue both index loads in parallel (no dependency)
    const int degraw = cursor[(size_t)w * CSTRIDE];
    const int myidx = (lane < CAP) ? csr[w * CAP + lane] : 0;
    const int deg = min(degraw, CAP);
    float a[8];
#pragma unroll
    for (int i = 0; i < 8; ++i) a[i] = 0.f;
    const unsigned short* fp = feat + c * 8;
    const int nb = (deg + 3) >> 2;    // 4-row batches, wave-uniform
    uint4 u[6];
#pragma unroll
    for (int b = 0; b < 6; ++b) {
        if (b < nb) {                 // wave-uniform branch: loads issue back-to-back
            int r = 4 * b + g;
            int s = __shfl(myidx, r < deg ? r : 0);
            u[b] = *(const uint4*)(fp + (size_t)s * C);
        }
    }
#pragma unroll
    for (int b = 0; b < 6; ++b) {
        if (b < nb) {
            if (4 * b + g < deg) acc8(a, u[b]);
        }
    }
    if (nb > 6) {                     // rare tail, wave-uniform
        for (int b = 6; b < nb; ++b) {
            int r = 4 * b + g;
            int s = __shfl(myidx, r < deg ? r : 0);
            uint4 uu = *(const uint4*)(fp + (size_t)s * C);
            if (r < deg) acc8(a, uu);
        }
    }
    // sum the 4 row-groups
#pragma unroll
    for (int i = 0; i < 8; ++i) {
        a[i] += __shfl_xor(a[i], 16);
        a[i] += __shfl_xor(a[i], 32);
    }
    const float inv = 1.0f / fmaxf((float)deg, 1.0f);
    if (g == 0) {
        unsigned int o[4];
#pragma unroll
        for (int i = 0; i < 4; ++i)
            o[i] = (unsigned)f2bf(a[2 * i] * inv) |
                   ((unsigned)f2bf(a[2 * i + 1] * inv) << 16);
        *(uint4*)(Fm + (size_t)w * C + c * 8) = *(const uint4*)o;
    }
}

// ---- GEMM: out[n][j] = sum_k A[n][k]*Wc[j][k] + bias[j]
// A = [Fm | Self] (two [*,128] bf16 matrices), M = NPAD, N = 128, K = 256
__global__ __launch_bounds__(256) void sage_gemm(
    const unsigned short* __restrict__ Fm,    // [NPAD,128] bf16 (mean)
    const unsigned short* __restrict__ Self,  // [NPAD,128] bf16 (self feats)
    const unsigned short* __restrict__ Wc,    // [128,256] bf16
    const float* __restrict__ bias,           // [128]
    void* __restrict__ outv, int relu, int obf16) {
    __shared__ unsigned short wl[128 * 264];  // pitch 264 shorts (bank shift 4)
    for (int cidx = threadIdx.x; cidx < 4096; cidx += 256) {
        int row = cidx >> 5, chunk = cidx & 31;
        const uint4 v = *(const uint4*)(Wc + row * 256 + chunk * 8);
        *(uint4*)(&wl[row * 264 + chunk * 8]) = v;
    }
    __syncthreads();

    const int wave = threadIdx.x >> 6;
    const int lane = threadIdx.x & 63;
    const int m = lane & 15;
    const int q = lane >> 4;
    const int tile0 = blockIdx.x * 8 + wave * 2;

    const size_t rowoff = (size_t)(tile0 * 16 + m) * C + q * 8;
    const unsigned short* am = Fm + rowoff;
    const unsigned short* as = Self + rowoff;

    f32x4 acc[2][8];
#pragma unroll
    for (int t = 0; t < 2; ++t)
#pragma unroll
        for (int j = 0; j < 8; ++j) acc[t][j] = (f32x4){0.f, 0.f, 0.f, 0.f};

#pragma unroll
    for (int kt = 0; kt < 8; ++kt) {
        const unsigned short* A = (kt < 4) ? am : as;
        const int ko = (kt & 3) * 32;
        bf16x8 af0 = *(const bf16x8*)(A + ko);
        bf16x8 af1 = *(const bf16x8*)(A + 16 * C + ko);
#pragma unroll
        for (int jt = 0; jt < 8; ++jt) {
            bf16x8 bfrag = *(const bf16x8*)(&wl[(jt * 16 + m) * 264 + kt * 32 + q * 8]);
            acc[0][jt] = __builtin_amdgcn_mfma_f32_16x16x32_bf16(af0, bfrag, acc[0][jt], 0, 0, 0);
            acc[1][jt] = __builtin_amdgcn_mfma_f32_16x16x32_bf16(af1, bfrag, acc[1][jt], 0, 0, 0);
        }
    }

#pragma unroll
    for (int t = 0; t < 2; ++t) {
        int rbase = (tile0 + t) * 16 + q * 4;
#pragma unroll
        for (int r = 0; r < 4; ++r) {
            int row = rbase + r;
            if (row < N_NODES) {
#pragma unroll
                for (int jt = 0; jt < 8; ++jt) {
                    int col = jt * 16 + m;
                    float v = acc[t][jt][r] + bias[col];
                    if (relu) v = fmaxf(v, 0.0f);
                    if (obf16)
                        ((unsigned short*)outv)[(size_t)row * C + col] = f2bf(v);
                    else
                        ((float*)outv)[(size_t)row * C + col] = v;
                }
            }
        }
    }
}

extern "C" void kernel_launch(void* const* d_in, const int* in_sizes, int n_in,
                              void* d_out, int out_size, void* d_ws, size_t ws_size,
                              hipStream_t stream) {
    const float* x = (const float*)d_in[0];
    const int* edge = (const int*)d_in[1];   // int64 in reference -> int32 in harness
    const float* Wl1 = (const float*)d_in[2];
    const float* bl1 = (const float*)d_in[3];
    const float* Wr1 = (const float*)d_in[4];
    const float* Wl2 = (const float*)d_in[5];
    const float* bl2 = (const float*)d_in[6];
    const float* Wr2 = (const float*)d_in[7];
    float* out = (float*)d_out;

    const int E = in_sizes[1] / 2;
    const int* src = edge;
    const int* dst = edge + E;

    // workspace layout
    char* ws = (char*)d_ws;
    size_t off = 0;
    int* cursor = (int*)(ws + off);           off += (size_t)N_NODES * CSTRIDE * 4; // 6.4 MB (1 line/node)
    off = (off + 511) & ~511ull;
    int* csr = (int*)(ws + off);              off += (size_t)N_NODES * CAP * 4;     // 9.6 MB
    off = (off + 511) & ~511ull;
    unsigned short* Xb = (unsigned short*)(ws + off); off += (size_t)NPAD * C * 2;  // 12.8 MB
    unsigned short* Fm = (unsigned short*)(ws + off); off += (size_t)NPAD * C * 2;  // 12.8 MB
    unsigned short* h  = (unsigned short*)(ws + off); off += (size_t)NPAD * C * 2;  // 12.8 MB
    unsigned short* Wc1 = (unsigned short*)(ws + off); off += 128 * 256 * 2;
    unsigned short* Wc2 = (unsigned short*)(ws + off); off += 128 * 256 * 2;
    (void)ws_size;

    const int edgeBlocks = (E + 255) / 256;
    const int gatherBlocks = (NPAD * 64) / 256;   // one wave per node

    // padded-CSR build + feature/weight conversion (2 dispatches)
    hipMemsetAsync(cursor, 0, (size_t)N_NODES * CSTRIDE * 4, stream);
    buildfill_kernel<<<edgeBlocks + XPREP_BLOCKS + WPREP_BLOCKS, 256, 0, stream>>>(
        src, dst, E, edgeBlocks, cursor, csr, x, Xb, Wl1, Wr1, Wl2, Wr2, Wc1, Wc2);

    // layer 1
    gather_kernel<<<gatherBlocks, 256, 0, stream>>>(Xb, cursor, csr, Fm);
    sage_gemm<<<GEMM_BLOCKS, 256, 0, stream>>>(Fm, Xb, Wc1, bl1, h, 1, 1);

    // layer 2
    gather_kernel<<<gatherBlocks, 256, 0, stream>>>(h, cursor, csr, Fm);
    sage_gemm<<<GEMM_BLOCKS, 256, 0, stream>>>(Fm, h, Wc2, bl2, out, 0, 0);
}